// Round 10
// baseline (159.486 us; speedup 1.0000x reference)
//
#include <hip/hip_runtime.h>
#include <cstdint>

typedef _Float16 half8 __attribute__((ext_vector_type(8)));
typedef float f32x4 __attribute__((ext_vector_type(4)));

#define LN_EPS 1e-5f

__device__ __forceinline__ float dot4(float4 a, float4 b) {
  return a.x*b.x + a.y*b.y + a.z*b.z + a.w*b.w;
}

// ============ K1 (k_pre): blocks 0..255 = mask (1 p-row each); 256..2303 = LN stats.
// FROZEN (round-2 verified form).
__global__ __launch_bounds__(256) void k_pre(
    const float* __restrict__ x, const float* __restrict__ few, const float* __restrict__ feb,
    const float* __restrict__ emb_pr, const float* __restrict__ lnp_w, const float* __restrict__ lnp_b,
    const float* __restrict__ prev, const float* __restrict__ W, const float* __restrict__ Wb,
    const float* __restrict__ emb_col, const float* __restrict__ lnc_w, const float* __restrict__ lnc_b,
    float2* __restrict__ stats2, float* __restrict__ mask_f32, _Float16* __restrict__ mask_f16)
{
  __shared__ __align__(16) struct {
    float xin[512];          // [LN(emb_pr[p]) | prev[p]]
    float xq[256];           // x_prompt row
    float sc[256];           // scores
    float wr1[4], wr2[4];
  } sm;

  int t = threadIdx.x, w = t >> 6, lane = t & 63;

  if (blockIdx.x >= 256) {
    // ================= stats role (wave-autonomous) =================
    int bid = blockIdx.x - 256;
    int b = bid >> 3;
    int cg = (bid & 7) * 4 + w;
    int c0 = cg * 8;
    float xv[8];
    #pragma unroll
    for (int j = 0; j < 8; ++j) xv[j] = x[b*256 + c0 + j];
    float s1[8], s2[8];
    #pragma unroll
    for (int j = 0; j < 8; ++j) { s1[j] = 0.f; s2[j] = 0.f; }
    #pragma unroll
    for (int j = 0; j < 8; ++j) {
      float4 fw = ((const float4*)few)[(c0+j)*64 + lane];
      float4 fb = ((const float4*)feb)[(c0+j)*64 + lane];
      float4 v;
      v.x = fmaxf(fb.x + xv[j]*fw.x, 0.f);
      v.y = fmaxf(fb.y + xv[j]*fw.y, 0.f);
      v.z = fmaxf(fb.z + xv[j]*fw.z, 0.f);
      v.w = fmaxf(fb.w + xv[j]*fw.w, 0.f);
      s1[j] += v.x + v.y + v.z + v.w;
      s2[j] += v.x*v.x + v.y*v.y + v.z*v.z + v.w*v.w;
    }
    #pragma unroll
    for (int o = 32; o > 0; o >>= 1) {
      #pragma unroll
      for (int j = 0; j < 8; ++j) { s1[j] += __shfl_xor(s1[j], o); s2[j] += __shfl_xor(s2[j], o); }
    }
    float mu[8], rs[8];
    #pragma unroll
    for (int j = 0; j < 8; ++j) {
      mu[j] = s1[j] * (1.0f/256.0f);
      float var = s2[j] * (1.0f/256.0f) - mu[j]*mu[j];
      rs[j] = rsqrtf(var + LN_EPS);
    }
    float muv = mu[0], rsv = rs[0];
    #pragma unroll
    for (int j = 1; j < 8; ++j) {
      muv = (lane == j) ? mu[j] : muv;
      rsv = (lane == j) ? rs[j] : rsv;
    }
    if (lane < 8) stats2[b*256 + c0 + lane] = make_float2(muv, rsv);
    return;
  }

  // ================= mask role (p = blockIdx.x) =================
  int p = blockIdx.x;
  int q = t & 3, g = t >> 2;

  // P1
  {
    float4 v = ((const float4*)emb_pr)[p*64 + lane];
    float s1 = v.x + v.y + v.z + v.w;
    float s2 = v.x*v.x + v.y*v.y + v.z*v.z + v.w*v.w;
    #pragma unroll
    for (int o = 32; o > 0; o >>= 1) { s1 += __shfl_xor(s1, o); s2 += __shfl_xor(s2, o); }
    float mu = s1 * (1.0f/256.0f);
    float var = s2 * (1.0f/256.0f) - mu*mu;
    float rsv = rsqrtf(var + LN_EPS);
    float4 w4 = ((const float4*)lnp_w)[lane];
    float4 b4 = ((const float4*)lnp_b)[lane];
    float4 y;
    y.x = (v.x-mu)*rsv*w4.x + b4.x;  y.y = (v.y-mu)*rsv*w4.y + b4.y;
    y.z = (v.z-mu)*rsv*w4.z + b4.z;  y.w = (v.w-mu)*rsv*w4.w + b4.w;
    if (w == 0) {
      ((float4*)sm.xin)[lane] = y;
      ((float4*)sm.xin)[64 + lane] = ((const float4*)prev)[p*64 + lane];
    }
  }
  __syncthreads();

  // P2
  {
    float acc[4] = {0.f, 0.f, 0.f, 0.f};
    #pragma unroll 4
    for (int j = 0; j < 32; ++j) {
      int k4 = j*4 + q;
      float4 xv = ((const float4*)sm.xin)[k4];
      #pragma unroll
      for (int pp = 0; pp < 4; ++pp) {
        int d = pp*64 + g;
        float4 wv = ((const float4*)W)[d*128 + k4];
        acc[pp] += dot4(wv, xv);
      }
    }
    #pragma unroll
    for (int pp = 0; pp < 4; ++pp) {
      acc[pp] += __shfl_xor(acc[pp], 1);
      acc[pp] += __shfl_xor(acc[pp], 2);
    }
    if (q == 0) {
      #pragma unroll
      for (int pp = 0; pp < 4; ++pp) {
        int d = pp*64 + g;
        sm.xq[d] = acc[pp] + Wb[d] + emb_pr[p*256 + d];
      }
    }
  }
  __syncthreads();

  // P3
  {
    float s1[4] = {0,0,0,0}, s2[4] = {0,0,0,0};
    #pragma unroll 4
    for (int j = 0; j < 16; ++j) {
      int k4 = j*4 + q;
      #pragma unroll
      for (int pp = 0; pp < 4; ++pp) {
        float4 v = ((const float4*)emb_col)[(pp*64+g)*64 + k4];
        s1[pp] += v.x + v.y + v.z + v.w;
        s2[pp] += v.x*v.x + v.y*v.y + v.z*v.z + v.w*v.w;
      }
    }
    float mu[4], rs[4];
    #pragma unroll
    for (int pp = 0; pp < 4; ++pp) {
      s1[pp] += __shfl_xor(s1[pp], 1);  s1[pp] += __shfl_xor(s1[pp], 2);
      s2[pp] += __shfl_xor(s2[pp], 1);  s2[pp] += __shfl_xor(s2[pp], 2);
      mu[pp] = s1[pp] * (1.0f/256.0f);
      float var = s2[pp] * (1.0f/256.0f) - mu[pp]*mu[pp];
      rs[pp] = rsqrtf(var + LN_EPS);
    }
    float acc[4] = {0.f, 0.f, 0.f, 0.f};
    #pragma unroll 4
    for (int j = 0; j < 16; ++j) {
      int k4 = j*4 + q;
      float4 lw4 = ((const float4*)lnc_w)[k4];
      float4 lb4 = ((const float4*)lnc_b)[k4];
      float4 xv = ((const float4*)sm.xq)[k4];
      #pragma unroll
      for (int pp = 0; pp < 4; ++pp) {
        float4 v = ((const float4*)emb_col)[(pp*64+g)*64 + k4];
        float4 nc;
        nc.x = (v.x-mu[pp])*rs[pp]*lw4.x + lb4.x;
        nc.y = (v.y-mu[pp])*rs[pp]*lw4.y + lb4.y;
        nc.z = (v.z-mu[pp])*rs[pp]*lw4.z + lb4.z;
        nc.w = (v.w-mu[pp])*rs[pp]*lw4.w + lb4.w;
        acc[pp] += dot4(nc, xv);
      }
    }
    #pragma unroll
    for (int pp = 0; pp < 4; ++pp) {
      acc[pp] += __shfl_xor(acc[pp], 1);
      acc[pp] += __shfl_xor(acc[pp], 2);
    }
    if (q == 0) {
      #pragma unroll
      for (int pp = 0; pp < 4; ++pp) sm.sc[pp*64 + g] = acc[pp];
    }
  }
  __syncthreads();

  // P4
  {
    float val = sm.sc[t];
    float m0 = val;
    #pragma unroll
    for (int o = 32; o > 0; o >>= 1) m0 = fmaxf(m0, __shfl_xor(m0, o));
    if (lane == 0) sm.wr1[w] = m0;
    __syncthreads();
    float M = fmaxf(fmaxf(sm.wr1[0], sm.wr1[1]), fmaxf(sm.wr1[2], sm.wr1[3]));
    float e = expf(val - M);
    float s = e;
    #pragma unroll
    for (int o = 32; o > 0; o >>= 1) s += __shfl_xor(s, o);
    if (lane == 0) sm.wr2[w] = s;
    __syncthreads();
    float S = sm.wr2[0] + sm.wr2[1] + sm.wr2[2] + sm.wr2[3];
    float mv = e / S;
    mask_f32[p*256 + t] = mv;
    mask_f16[p*256 + t] = (_Float16)mv;
  }
}

// ============ K2a (k_prod): v5's producer, writing the 32 KB fragment-format tile
// to global workspace instead of LDS. Pure streaming: 1 barrier (xrow/srow), no
// MFMA, ends. Tile format [kb][k8][n=64][8] is byte-identical to v5's Bs, so the
// GEMM reads fragments with unchanged indexing.
__global__ __launch_bounds__(256) void k_prod(
    const float* __restrict__ x, const float* __restrict__ few, const float* __restrict__ feb,
    const float* __restrict__ ln_emb_w, const float* __restrict__ ln_emb_b,
    const float2* __restrict__ stats2, _Float16* __restrict__ xemb)
{
  __shared__ float xrow[256];
  __shared__ __align__(8) float2 srow[256];

  const int t = threadIdx.x, w = t >> 6;
  const int b  = blockIdx.x >> 2;
  const int ds = (blockIdx.x & 3) * 64;
  const int dl = t & 63;
  const int d  = ds + dl;

  xrow[t] = x[b*256 + t];
  srow[t] = stats2[b*256 + t];
  const float lwv = ln_emb_w[d];
  const float lbv = ln_emb_b[d];
  __syncthreads();

  _Float16* xg = xemb + (size_t)blockIdx.x * 16384;

  #pragma unroll
  for (int kb = 0; kb < 4; ++kb) {
    float fwv[16], fbv[16];
    #pragma unroll
    for (int j = 0; j < 16; ++j) {
      int cl = kb*64 + w*16 + j;
      fwv[j] = few[cl*256 + d];
      fbv[j] = feb[cl*256 + d];
    }
    half8 h0, h1;
    #pragma unroll
    for (int j = 0; j < 16; ++j) {
      int cl = kb*64 + w*16 + j;
      float2 st = srow[cl];
      float v = fmaxf(fbv[j] + xrow[cl]*fwv[j], 0.f);
      _Float16 hh = (_Float16)((v - st.x) * st.y * lwv + lbv);
      if (j < 8) h0[j] = hh; else h1[j-8] = hh;
    }
    *(half8*)(xg + (size_t)((kb*8 + w*2 + 0)*64 + dl)*8) = h0;
    *(half8*)(xg + (size_t)((kb*8 + w*2 + 1)*64 + dl)*8) = h1;
  }
}

// ============ K2b (k_gemm): v5's MFMA sweep + epilogue with fragments loaded from
// global (L2). ZERO LDS, ZERO barriers -> no per-block serialization; ~8 blocks/CU
// co-resident; MFMA/VMEM overlap across waves hides all latency (m114 regime).
// Fragment maps and epilogue byte-identical to the verified v5.
__global__ __launch_bounds__(256) void k_gemm(
    const _Float16* __restrict__ xemb,
    const _Float16* __restrict__ mask_f16, const float* __restrict__ mask_f32,
    const float* __restrict__ ew, const float* __restrict__ eb,
    float* __restrict__ out)
{
  const int t = threadIdx.x, w = t >> 6, lane = t & 63;
  const int lm = lane & 15, quad = lane >> 4;
  const int b  = blockIdx.x >> 2;
  const int ds = (blockIdx.x & 3) * 64;

  const _Float16* xg = xemb + (size_t)blockIdx.x * 16384;

  f32x4 acc[4][4];
  #pragma unroll
  for (int i = 0; i < 4; ++i)
    #pragma unroll
    for (int j = 0; j < 4; ++j)
      acc[i][j] = (f32x4){0.f, 0.f, 0.f, 0.f};

  #pragma unroll
  for (int kb = 0; kb < 4; ++kb) {
    half8 mf[2][4];
    #pragma unroll
    for (int ks = 0; ks < 2; ++ks)
      #pragma unroll
      for (int nt = 0; nt < 4; ++nt)
        mf[ks][nt] = *(const half8*)(mask_f16 + (size_t)(w*64 + nt*16 + lm)*256 + kb*64 + ks*32 + quad*8);
    #pragma unroll
    for (int ks = 0; ks < 2; ++ks) {
      half8 xf[4];
      #pragma unroll
      for (int mt = 0; mt < 4; ++mt)
        xf[mt] = *(const half8*)(xg + (size_t)((kb*8 + ks*4 + quad)*64 + mt*16 + lm)*8);
      #pragma unroll
      for (int mt = 0; mt < 4; ++mt)
        #pragma unroll
        for (int nt = 0; nt < 4; ++nt)
          acc[mt][nt] = __builtin_amdgcn_mfma_f32_16x16x32_f16(xf[mt], mf[ks][nt], acc[mt][nt], 0, 0, 0);
    }
  }

  // epilogue (v5-verbatim): acc[mt][nt] -> row d = ds + mt*16 + quad*4 + r,
  // col p = w*64 + nt*16 + lm; float4 stores along d.
  const float ebv = eb[b];
  float sp[4], tb[4];
  #pragma unroll
  for (int nt = 0; nt < 4; ++nt) {
    int p = w*64 + nt*16 + lm;
    sp[nt] = 1.0f + ew[p];
    tb[nt] = mask_f32[b*256 + p] * ebv;
  }
  #pragma unroll
  for (int mt = 0; mt < 4; ++mt) {
    #pragma unroll
    for (int nt = 0; nt < 4; ++nt) {
      int p = w*64 + nt*16 + lm;
      int dd = ds + mt*16 + quad*4;
      f32x4 o = acc[mt][nt] * sp[nt] + tb[nt];
      *(f32x4*)(out + ((size_t)b << 16) + ((size_t)p << 8) + dd) = o;
    }
  }
}

// ============ Fallback: v5's fused k_main (verified 146.5 µs config), used only
// if the workspace is too small for the 33.5 MB xemb buffer.
__global__ __launch_bounds__(256) void k_main_fused(
    const float* __restrict__ x, const float* __restrict__ few, const float* __restrict__ feb,
    const float* __restrict__ ln_emb_w, const float* __restrict__ ln_emb_b,
    const float2* __restrict__ stats2,
    const _Float16* __restrict__ mask_f16, const float* __restrict__ mask_f32,
    const float* __restrict__ ew, const float* __restrict__ eb,
    float* __restrict__ out)
{
  __shared__ __align__(16) _Float16 Bs[4 * 8 * 64 * 8];   // 32 KB, [kb][k8][n=64][8]
  __shared__ float xrow[256];
  __shared__ __align__(8) float2 srow[256];

  const int t = threadIdx.x, w = t >> 6, lane = t & 63;
  const int lm = lane & 15, quad = lane >> 4;
  const int b  = blockIdx.x >> 2;
  const int ds = (blockIdx.x & 3) * 64;
  const int dl = t & 63;
  const int d  = ds + dl;

  half8 mf0[2][4], mf1[2][4];
  #pragma unroll
  for (int ks = 0; ks < 2; ++ks)
    #pragma unroll
    for (int nt = 0; nt < 4; ++nt)
      mf0[ks][nt] = *(const half8*)(mask_f16 + (size_t)(w*64 + nt*16 + lm)*256 + ks*32 + quad*8);

  xrow[t] = x[b*256 + t];
  srow[t] = stats2[b*256 + t];
  const float lwv = ln_emb_w[d];
  const float lbv = ln_emb_b[d];

  f32x4 acc[4][4];
  #pragma unroll
  for (int i = 0; i < 4; ++i)
    #pragma unroll
    for (int j = 0; j < 4; ++j)
      acc[i][j] = (f32x4){0.f, 0.f, 0.f, 0.f};

  __syncthreads();

  #pragma unroll
  for (int kb = 0; kb < 4; ++kb) {
    float fwv[16], fbv[16];
    #pragma unroll
    for (int j = 0; j < 16; ++j) {
      int cl = kb*64 + w*16 + j;
      fwv[j] = few[cl*256 + d];
      fbv[j] = feb[cl*256 + d];
    }
    half8 h0, h1;
    #pragma unroll
    for (int j = 0; j < 16; ++j) {
      int cl = kb*64 + w*16 + j;
      float2 st = srow[cl];
      float v = fmaxf(fbv[j] + xrow[cl]*fwv[j], 0.f);
      _Float16 hh = (_Float16)((v - st.x) * st.y * lwv + lbv);
      if (j < 8) h0[j] = hh; else h1[j-8] = hh;
    }
    *(half8*)(&Bs[((kb*8 + w*2 + 0)*64 + dl)*8]) = h0;
    *(half8*)(&Bs[((kb*8 + w*2 + 1)*64 + dl)*8]) = h1;
  }
  __syncthreads();

#define MFMA_KB(KB, MFC, MFN, DO_PRE)                                           \
  {                                                                             \
    if (DO_PRE) {                                                               \
      _Pragma("unroll") for (int ks = 0; ks < 2; ++ks)                          \
        _Pragma("unroll") for (int nt = 0; nt < 4; ++nt)                        \
          MFN[ks][nt] = *(const half8*)(mask_f16 +                              \
              (size_t)(w*64 + nt*16 + lm)*256 + ((KB)+1)*64 + ks*32 + quad*8);  \
    }                                                                           \
    _Pragma("unroll") for (int ks = 0; ks < 2; ++ks) {                          \
      half8 xf[4];                                                              \
      _Pragma("unroll") for (int mt = 0; mt < 4; ++mt)                          \
        xf[mt] = *(const half8*)(&Bs[(((KB)*8 + ks*4 + quad)*64 + mt*16 + lm)*8]); \
      _Pragma("unroll") for (int mt = 0; mt < 4; ++mt)                          \
        _Pragma("unroll") for (int nt = 0; nt < 4; ++nt)                        \
          acc[mt][nt] = __builtin_amdgcn_mfma_f32_16x16x32_f16(                 \
              xf[mt], MFC[ks][nt], acc[mt][nt], 0, 0, 0);                       \
    }                                                                           \
  }

  MFMA_KB(0, mf0, mf1, 1)
  MFMA_KB(1, mf1, mf0, 1)
  MFMA_KB(2, mf0, mf1, 1)
  MFMA_KB(3, mf1, mf0, 0)
#undef MFMA_KB

  const float ebv = eb[b];
  float sp[4], tb[4];
  #pragma unroll
  for (int nt = 0; nt < 4; ++nt) {
    int p = w*64 + nt*16 + lm;
    sp[nt] = 1.0f + ew[p];
    tb[nt] = mask_f32[b*256 + p] * ebv;
  }
  #pragma unroll
  for (int mt = 0; mt < 4; ++mt) {
    #pragma unroll
    for (int nt = 0; nt < 4; ++nt) {
      int p = w*64 + nt*16 + lm;
      int dd = ds + mt*16 + quad*4;
      f32x4 o = acc[mt][nt] * sp[nt] + tb[nt];
      *(f32x4*)(out + ((size_t)b << 16) + ((size_t)p << 8) + dd) = o;
    }
  }
}

extern "C" void kernel_launch(void* const* d_in, const int* in_sizes, int n_in,
                              void* d_out, int out_size, void* d_ws, size_t ws_size,
                              hipStream_t stream) {
  const float* x        = (const float*)d_in[0];
  const float* prev     = (const float*)d_in[1];
  const float* few      = (const float*)d_in[2];
  const float* feb      = (const float*)d_in[3];
  const float* ln_emb_w = (const float*)d_in[4];
  const float* ln_emb_b = (const float*)d_in[5];
  const float* ln_col_w = (const float*)d_in[6];
  const float* ln_col_b = (const float*)d_in[7];
  const float* ln_pr_w  = (const float*)d_in[8];
  const float* ln_pr_b  = (const float*)d_in[9];
  const float* dimp_w   = (const float*)d_in[10];
  const float* dimp_b   = (const float*)d_in[11];
  const float* emb_col  = (const float*)d_in[12];
  const float* emb_pr   = (const float*)d_in[13];
  const float* ew       = (const float*)d_in[14];
  const float* eb       = (const float*)d_in[15];
  float* out = (float*)d_out;

  char* wsb = (char*)d_ws;
  float2*   ws_stats  = (float2*)(wsb);                  // 524,288 B
  float*    ws_mask   = (float*)(wsb + 524288);          // 262,144 B
  _Float16* ws_mask_h = (_Float16*)(wsb + 786432);       // 131,072 B
  _Float16* ws_xemb   = (_Float16*)(wsb + 917504);       // 33,554,432 B (split path)

  const size_t need = 917504 + (size_t)1024 * 16384 * sizeof(_Float16);

  k_pre<<<dim3(256 + 2048), dim3(256), 0, stream>>>(
      x, few, feb,
      emb_pr, ln_pr_w, ln_pr_b, prev, dimp_w, dimp_b,
      emb_col, ln_col_w, ln_col_b,
      ws_stats, ws_mask, ws_mask_h);

  if (ws_size >= need) {
    k_prod<<<dim3(1024), dim3(256), 0, stream>>>(
        x, few, feb, ln_emb_w, ln_emb_b, ws_stats, ws_xemb);
    k_gemm<<<dim3(1024), dim3(256), 0, stream>>>(
        ws_xemb, ws_mask_h, ws_mask, ew, eb, out);
  } else {
    k_main_fused<<<dim3(1024), dim3(256), 0, stream>>>(
        x, few, feb, ln_emb_w, ln_emb_b,
        ws_stats, ws_mask_h, ws_mask, ew, eb, out);
  }
}

// Round 11
// 146.629 us; speedup vs baseline: 1.0877x; 1.0877x over previous
//
#include <hip/hip_runtime.h>
#include <cstdint>

typedef _Float16 half8 __attribute__((ext_vector_type(8)));
typedef float f32x4 __attribute__((ext_vector_type(4)));

#define LN_EPS 1e-5f

__device__ __forceinline__ float dot4(float4 a, float4 b) {
  return a.x*b.x + a.y*b.y + a.z*b.z + a.w*b.w;
}

// ============ K1 (k_pre): blocks 0..255 = mask (1 p-row each); 256..2303 = LN stats.
// FROZEN (round-2 verified form).
__global__ __launch_bounds__(256) void k_pre(
    const float* __restrict__ x, const float* __restrict__ few, const float* __restrict__ feb,
    const float* __restrict__ emb_pr, const float* __restrict__ lnp_w, const float* __restrict__ lnp_b,
    const float* __restrict__ prev, const float* __restrict__ W, const float* __restrict__ Wb,
    const float* __restrict__ emb_col, const float* __restrict__ lnc_w, const float* __restrict__ lnc_b,
    float2* __restrict__ stats2, float* __restrict__ mask_f32, _Float16* __restrict__ mask_f16)
{
  __shared__ __align__(16) struct {
    float xin[512];          // [LN(emb_pr[p]) | prev[p]]
    float xq[256];           // x_prompt row
    float sc[256];           // scores
    float wr1[4], wr2[4];
  } sm;

  int t = threadIdx.x, w = t >> 6, lane = t & 63;

  if (blockIdx.x >= 256) {
    // ================= stats role (wave-autonomous) =================
    int bid = blockIdx.x - 256;
    int b = bid >> 3;
    int cg = (bid & 7) * 4 + w;
    int c0 = cg * 8;
    float xv[8];
    #pragma unroll
    for (int j = 0; j < 8; ++j) xv[j] = x[b*256 + c0 + j];
    float s1[8], s2[8];
    #pragma unroll
    for (int j = 0; j < 8; ++j) { s1[j] = 0.f; s2[j] = 0.f; }
    #pragma unroll
    for (int j = 0; j < 8; ++j) {
      float4 fw = ((const float4*)few)[(c0+j)*64 + lane];
      float4 fb = ((const float4*)feb)[(c0+j)*64 + lane];
      float4 v;
      v.x = fmaxf(fb.x + xv[j]*fw.x, 0.f);
      v.y = fmaxf(fb.y + xv[j]*fw.y, 0.f);
      v.z = fmaxf(fb.z + xv[j]*fw.z, 0.f);
      v.w = fmaxf(fb.w + xv[j]*fw.w, 0.f);
      s1[j] += v.x + v.y + v.z + v.w;
      s2[j] += v.x*v.x + v.y*v.y + v.z*v.z + v.w*v.w;
    }
    #pragma unroll
    for (int o = 32; o > 0; o >>= 1) {
      #pragma unroll
      for (int j = 0; j < 8; ++j) { s1[j] += __shfl_xor(s1[j], o); s2[j] += __shfl_xor(s2[j], o); }
    }
    float mu[8], rs[8];
    #pragma unroll
    for (int j = 0; j < 8; ++j) {
      mu[j] = s1[j] * (1.0f/256.0f);
      float var = s2[j] * (1.0f/256.0f) - mu[j]*mu[j];
      rs[j] = rsqrtf(var + LN_EPS);
    }
    float muv = mu[0], rsv = rs[0];
    #pragma unroll
    for (int j = 1; j < 8; ++j) {
      muv = (lane == j) ? mu[j] : muv;
      rsv = (lane == j) ? rs[j] : rsv;
    }
    if (lane < 8) stats2[b*256 + c0 + lane] = make_float2(muv, rsv);
    return;
  }

  // ================= mask role (p = blockIdx.x) =================
  int p = blockIdx.x;
  int q = t & 3, g = t >> 2;

  // P1
  {
    float4 v = ((const float4*)emb_pr)[p*64 + lane];
    float s1 = v.x + v.y + v.z + v.w;
    float s2 = v.x*v.x + v.y*v.y + v.z*v.z + v.w*v.w;
    #pragma unroll
    for (int o = 32; o > 0; o >>= 1) { s1 += __shfl_xor(s1, o); s2 += __shfl_xor(s2, o); }
    float mu = s1 * (1.0f/256.0f);
    float var = s2 * (1.0f/256.0f) - mu*mu;
    float rsv = rsqrtf(var + LN_EPS);
    float4 w4 = ((const float4*)lnp_w)[lane];
    float4 b4 = ((const float4*)lnp_b)[lane];
    float4 y;
    y.x = (v.x-mu)*rsv*w4.x + b4.x;  y.y = (v.y-mu)*rsv*w4.y + b4.y;
    y.z = (v.z-mu)*rsv*w4.z + b4.z;  y.w = (v.w-mu)*rsv*w4.w + b4.w;
    if (w == 0) {
      ((float4*)sm.xin)[lane] = y;
      ((float4*)sm.xin)[64 + lane] = ((const float4*)prev)[p*64 + lane];
    }
  }
  __syncthreads();

  // P2
  {
    float acc[4] = {0.f, 0.f, 0.f, 0.f};
    #pragma unroll 4
    for (int j = 0; j < 32; ++j) {
      int k4 = j*4 + q;
      float4 xv = ((const float4*)sm.xin)[k4];
      #pragma unroll
      for (int pp = 0; pp < 4; ++pp) {
        int d = pp*64 + g;
        float4 wv = ((const float4*)W)[d*128 + k4];
        acc[pp] += dot4(wv, xv);
      }
    }
    #pragma unroll
    for (int pp = 0; pp < 4; ++pp) {
      acc[pp] += __shfl_xor(acc[pp], 1);
      acc[pp] += __shfl_xor(acc[pp], 2);
    }
    if (q == 0) {
      #pragma unroll
      for (int pp = 0; pp < 4; ++pp) {
        int d = pp*64 + g;
        sm.xq[d] = acc[pp] + Wb[d] + emb_pr[p*256 + d];
      }
    }
  }
  __syncthreads();

  // P3
  {
    float s1[4] = {0,0,0,0}, s2[4] = {0,0,0,0};
    #pragma unroll 4
    for (int j = 0; j < 16; ++j) {
      int k4 = j*4 + q;
      #pragma unroll
      for (int pp = 0; pp < 4; ++pp) {
        float4 v = ((const float4*)emb_col)[(pp*64+g)*64 + k4];
        s1[pp] += v.x + v.y + v.z + v.w;
        s2[pp] += v.x*v.x + v.y*v.y + v.z*v.z + v.w*v.w;
      }
    }
    float mu[4], rs[4];
    #pragma unroll
    for (int pp = 0; pp < 4; ++pp) {
      s1[pp] += __shfl_xor(s1[pp], 1);  s1[pp] += __shfl_xor(s1[pp], 2);
      s2[pp] += __shfl_xor(s2[pp], 1);  s2[pp] += __shfl_xor(s2[pp], 2);
      mu[pp] = s1[pp] * (1.0f/256.0f);
      float var = s2[pp] * (1.0f/256.0f) - mu[pp]*mu[pp];
      rs[pp] = rsqrtf(var + LN_EPS);
    }
    float acc[4] = {0.f, 0.f, 0.f, 0.f};
    #pragma unroll 4
    for (int j = 0; j < 16; ++j) {
      int k4 = j*4 + q;
      float4 lw4 = ((const float4*)lnc_w)[k4];
      float4 lb4 = ((const float4*)lnc_b)[k4];
      float4 xv = ((const float4*)sm.xq)[k4];
      #pragma unroll
      for (int pp = 0; pp < 4; ++pp) {
        float4 v = ((const float4*)emb_col)[(pp*64+g)*64 + k4];
        float4 nc;
        nc.x = (v.x-mu[pp])*rs[pp]*lw4.x + lb4.x;
        nc.y = (v.y-mu[pp])*rs[pp]*lw4.y + lb4.y;
        nc.z = (v.z-mu[pp])*rs[pp]*lw4.z + lb4.z;
        nc.w = (v.w-mu[pp])*rs[pp]*lw4.w + lb4.w;
        acc[pp] += dot4(nc, xv);
      }
    }
    #pragma unroll
    for (int pp = 0; pp < 4; ++pp) {
      acc[pp] += __shfl_xor(acc[pp], 1);
      acc[pp] += __shfl_xor(acc[pp], 2);
    }
    if (q == 0) {
      #pragma unroll
      for (int pp = 0; pp < 4; ++pp) sm.sc[pp*64 + g] = acc[pp];
    }
  }
  __syncthreads();

  // P4
  {
    float val = sm.sc[t];
    float m0 = val;
    #pragma unroll
    for (int o = 32; o > 0; o >>= 1) m0 = fmaxf(m0, __shfl_xor(m0, o));
    if (lane == 0) sm.wr1[w] = m0;
    __syncthreads();
    float M = fmaxf(fmaxf(sm.wr1[0], sm.wr1[1]), fmaxf(sm.wr1[2], sm.wr1[3]));
    float e = expf(val - M);
    float s = e;
    #pragma unroll
    for (int o = 32; o > 0; o >>= 1) s += __shfl_xor(s, o);
    if (lane == 0) sm.wr2[w] = s;
    __syncthreads();
    float S = sm.wr2[0] + sm.wr2[1] + sm.wr2[2] + sm.wr2[3];
    float mv = e / S;
    mask_f32[p*256 + t] = mv;
    mask_f16[p*256 + t] = (_Float16)mv;
  }
}

// ============ K2 (k_main) v5: BARRIER-MINIMAL (best verified, 146.5 µs total).
// Single 32 KB Bs holds all K=256 of x_emb; producer sweeps all 4 kb chunks with
// zero intervening barriers; ONE barrier; then 8 MFMA phases with zero barriers
// (mask frags ping-pong prefetched one kb ahead). 2 barriers/block total.
__global__ __launch_bounds__(256) void k_main(
    const float* __restrict__ x, const float* __restrict__ few, const float* __restrict__ feb,
    const float* __restrict__ ln_emb_w, const float* __restrict__ ln_emb_b,
    const float2* __restrict__ stats2,
    const _Float16* __restrict__ mask_f16, const float* __restrict__ mask_f32,
    const float* __restrict__ ew, const float* __restrict__ eb,
    float* __restrict__ out)
{
  __shared__ __align__(16) _Float16 Bs[4 * 8 * 64 * 8];   // 32 KB, [kb][k8][n=64][8]
  __shared__ float xrow[256];
  __shared__ __align__(8) float2 srow[256];

  const int t = threadIdx.x, w = t >> 6, lane = t & 63;
  const int lm = lane & 15, quad = lane >> 4;
  const int b  = blockIdx.x >> 2;
  const int ds = (blockIdx.x & 3) * 64;
  const int dl = t & 63;
  const int d  = ds + dl;

  // mask frags for kb=0 — issued first, in flight across the whole producer sweep
  half8 mf0[2][4], mf1[2][4];
  #pragma unroll
  for (int ks = 0; ks < 2; ++ks)
    #pragma unroll
    for (int nt = 0; nt < 4; ++nt)
      mf0[ks][nt] = *(const half8*)(mask_f16 + (size_t)(w*64 + nt*16 + lm)*256 + ks*32 + quad*8);

  xrow[t] = x[b*256 + t];
  srow[t] = stats2[b*256 + t];
  const float lwv = ln_emb_w[d];
  const float lbv = ln_emb_b[d];

  f32x4 acc[4][4];
  #pragma unroll
  for (int i = 0; i < 4; ++i)
    #pragma unroll
    for (int j = 0; j < 4; ++j)
      acc[i][j] = (f32x4){0.f, 0.f, 0.f, 0.f};

  __syncthreads();              // barrier 1: xrow/srow visible

  // producer sweep: all 256 c, no barriers between chunks
  #pragma unroll
  for (int kb = 0; kb < 4; ++kb) {
    float fwv[16], fbv[16];
    #pragma unroll
    for (int j = 0; j < 16; ++j) {
      int cl = kb*64 + w*16 + j;
      fwv[j] = few[cl*256 + d];
      fbv[j] = feb[cl*256 + d];
    }
    half8 h0, h1;
    #pragma unroll
    for (int j = 0; j < 16; ++j) {
      int cl = kb*64 + w*16 + j;
      float2 st = srow[cl];
      float v = fmaxf(fbv[j] + xrow[cl]*fwv[j], 0.f);
      _Float16 hh = (_Float16)((v - st.x) * st.y * lwv + lbv);
      if (j < 8) h0[j] = hh; else h1[j-8] = hh;
    }
    *(half8*)(&Bs[((kb*8 + w*2 + 0)*64 + dl)*8]) = h0;
    *(half8*)(&Bs[((kb*8 + w*2 + 1)*64 + dl)*8]) = h1;
  }
  __syncthreads();              // barrier 2: all of Bs ready

  // MFMA sweep: 8 phases, zero barriers. MFC = current mask frags, MFN = next
  // buffer (prefetch issued before the MFMAs so latency hides under 2 ks phases).
#define MFMA_KB(KB, MFC, MFN, DO_PRE)                                           \
  {                                                                             \
    if (DO_PRE) {                                                               \
      _Pragma("unroll") for (int ks = 0; ks < 2; ++ks)                          \
        _Pragma("unroll") for (int nt = 0; nt < 4; ++nt)                        \
          MFN[ks][nt] = *(const half8*)(mask_f16 +                              \
              (size_t)(w*64 + nt*16 + lm)*256 + ((KB)+1)*64 + ks*32 + quad*8);  \
    }                                                                           \
    _Pragma("unroll") for (int ks = 0; ks < 2; ++ks) {                          \
      half8 xf[4];                                                              \
      _Pragma("unroll") for (int mt = 0; mt < 4; ++mt)                          \
        xf[mt] = *(const half8*)(&Bs[(((KB)*8 + ks*4 + quad)*64 + mt*16 + lm)*8]); \
      _Pragma("unroll") for (int mt = 0; mt < 4; ++mt)                          \
        _Pragma("unroll") for (int nt = 0; nt < 4; ++nt)                        \
          acc[mt][nt] = __builtin_amdgcn_mfma_f32_16x16x32_f16(                 \
              xf[mt], MFC[ks][nt], acc[mt][nt], 0, 0, 0);                       \
    }                                                                           \
  }

  MFMA_KB(0, mf0, mf1, 1)
  MFMA_KB(1, mf1, mf0, 1)
  MFMA_KB(2, mf0, mf1, 1)
  MFMA_KB(3, mf1, mf0, 0)
#undef MFMA_KB

  // epilogue: acc[mt][nt] -> row d = ds + mt*16 + quad*4 + r,
  // col p = w*64 + nt*16 + lm; float4 stores along d.
  const float ebv = eb[b];
  float sp[4], tb[4];
  #pragma unroll
  for (int nt = 0; nt < 4; ++nt) {
    int p = w*64 + nt*16 + lm;
    sp[nt] = 1.0f + ew[p];
    tb[nt] = mask_f32[b*256 + p] * ebv;
  }
  #pragma unroll
  for (int mt = 0; mt < 4; ++mt) {
    #pragma unroll
    for (int nt = 0; nt < 4; ++nt) {
      int p = w*64 + nt*16 + lm;
      int dd = ds + mt*16 + quad*4;
      f32x4 o = acc[mt][nt] * sp[nt] + tb[nt];
      *(f32x4*)(out + ((size_t)b << 16) + ((size_t)p << 8) + dd) = o;
    }
  }
}

extern "C" void kernel_launch(void* const* d_in, const int* in_sizes, int n_in,
                              void* d_out, int out_size, void* d_ws, size_t ws_size,
                              hipStream_t stream) {
  const float* x        = (const float*)d_in[0];
  const float* prev     = (const float*)d_in[1];
  const float* few      = (const float*)d_in[2];
  const float* feb      = (const float*)d_in[3];
  const float* ln_emb_w = (const float*)d_in[4];
  const float* ln_emb_b = (const float*)d_in[5];
  const float* ln_col_w = (const float*)d_in[6];
  const float* ln_col_b = (const float*)d_in[7];
  const float* ln_pr_w  = (const float*)d_in[8];
  const float* ln_pr_b  = (const float*)d_in[9];
  const float* dimp_w   = (const float*)d_in[10];
  const float* dimp_b   = (const float*)d_in[11];
  const float* emb_col  = (const float*)d_in[12];
  const float* emb_pr   = (const float*)d_in[13];
  const float* ew       = (const float*)d_in[14];
  const float* eb       = (const float*)d_in[15];
  float* out = (float*)d_out;

  char* wsb = (char*)d_ws;
  float2*   ws_stats  = (float2*)(wsb);                  // 524,288 B
  float*    ws_mask   = (float*)(wsb + 524288);          // 262,144 B
  _Float16* ws_mask_h = (_Float16*)(wsb + 786432);       // 131,072 B

  k_pre<<<dim3(256 + 2048), dim3(256), 0, stream>>>(
      x, few, feb,
      emb_pr, ln_pr_w, ln_pr_b, prev, dimp_w, dimp_b,
      emb_col, ln_col_w, ln_col_b,
      ws_stats, ws_mask, ws_mask_h);
  k_main<<<dim3(1024), dim3(256), 0, stream>>>(
      x, few, feb, ln_emb_w, ln_emb_b,
      ws_stats, ws_mask_h, ws_mask, ew, eb, out);
}